// Round 1
// baseline (9073.222 us; speedup 1.0000x reference)
//
#include <hip/hip_runtime.h>
#include <hip/hip_bf16.h>

// ---------------------------------------------------------------------------
// Bidirectional 2-layer LSTM (B=128, T=512, H=256, INPUT=4) + mean-pool + FC.
//
// Persistent-RNN design:
//  - Recurrent weights live in VGPRs as MFMA B-fragments, loaded once,
//    reused across all 512 time steps.
//  - Per direction: 16 gate-split blocks (16 hidden units each; a wave's 4
//    N-tiles are exactly i/f/g/o of the same 16 hidden units -> cell update
//    is pure per-lane VALU). Batch split 2-way (L0) / 4-way (L1).
//  - Per-step cross-block h exchange via global bf16 buffers + per-block
//    flags (release store / relaxed spin + agent fences; cross-XCD safe).
//  - Layer 1 folds its input GEMM into the recurrence: K = 768 =
//    [h1_prev(256) | h0_fwd(256) | h0_bwd(256)], staged in LDS per step.
//  - Mean-pool accumulated in registers inside layer-1 kernel.
// ---------------------------------------------------------------------------

typedef __bf16 bf16;
typedef __bf16 bf16x8 __attribute__((ext_vector_type(8)));
typedef float  f32x4  __attribute__((ext_vector_type(4)));

#define T_SEQ 512
#define BATCH 128
#define HID   256

// ws layout (bytes)
#define H0_BYTES   67239936ULL                  // bf16 [2][513][128][256]
#define H1_BYTES   262144ULL                    // bf16 [2][2][128][256] ring
#define POOL_BYTES 262144ULL                    // f32  [2][128][256]
#define FL0_OFF    (H0_BYTES + H1_BYTES + POOL_BYTES)
#define FL1_OFF    (FL0_OFF + 256ULL)

__device__ __forceinline__ float fsig(float v) {
    return __builtin_amdgcn_rcpf(1.0f + __expf(-v));
}
__device__ __forceinline__ float ftanh(float v) {
    float a = fabsf(v);
    float e = __expf(-2.0f * a);
    float r = (1.0f - e) * __builtin_amdgcn_rcpf(1.0f + e);
    return v < 0.0f ? -r : r;
}

// ---------------------------------------------------------------------------
__global__ void k_init(unsigned int* ws_u, int* flags0, int* flags1) {
    const int t = blockIdx.x * 256 + threadIdx.x;       // 0..16383
    // h0[0][slot0] : 32768 bf16 = 16384 uints
    ws_u[t] = 0u;
    // h0[1][slot0] : elem offset 513*32768 -> uint 513*16384
    ws_u[(size_t)513 * 16384 + t] = 0u;
    unsigned int* h1u = ws_u + (H0_BYTES / 4);
    h1u[t] = 0u;                                        // h1 dir0 parity0
    h1u[32768 + t] = 0u;                                // h1 dir1 parity0
    if (t < 64)  flags0[t] = 0;
    if (t < 128) flags1[t] = 0;
}

// ---------------------------------------------------------------------------
// Layer 0: grid 64 = dir(2) x batch-half(2) x gate-group(16). 256 thr/block.
// Block: M=64 batch rows, N=64 gate cols (i,f,g,o of 16 hidden units), K=256.
// Waves split M (16 rows each). Weights: 4x8 B-fragments = 128 VGPRs.
// x contribution (K=4) done as per-lane FMAs into the accumulator init.
// ---------------------------------------------------------------------------
__global__ __launch_bounds__(256, 1) void k_l0(
    const float* __restrict__ x, const float* __restrict__ wih,
    const float* __restrict__ whh, const float* __restrict__ bih,
    const float* __restrict__ bhh, bf16* __restrict__ h0,
    int* __restrict__ flags)
{
    const int blk = blockIdx.x;
    const int dir = blk >> 5, bh = (blk >> 4) & 1, g = blk & 15;
    const int tid = threadIdx.x, wave = tid >> 6, lane = tid & 63;
    const int l15 = lane & 15, q = lane >> 4;
    const int j = g * 16 + l15;                 // hidden unit (column)

    // B fragments: Bf[gate][kt], n = gate*256 + j, k = kt*32 + q*8 .. +8
    bf16x8 Bf[4][8];
#pragma unroll
    for (int tg = 0; tg < 4; ++tg) {
        const float* wr = whh + ((size_t)(dir * 1024 + tg * 256 + j)) * 256 + q * 8;
#pragma unroll
        for (int kt = 0; kt < 8; ++kt) {
            f32x4 aa = *(const f32x4*)(wr + kt * 32);
            f32x4 bb = *(const f32x4*)(wr + kt * 32 + 4);
            bf16x8 f;
            f[0] = (bf16)aa[0]; f[1] = (bf16)aa[1]; f[2] = (bf16)aa[2]; f[3] = (bf16)aa[3];
            f[4] = (bf16)bb[0]; f[5] = (bf16)bb[1]; f[6] = (bf16)bb[2]; f[7] = (bf16)bb[3];
            Bf[tg][kt] = f;
        }
    }
    float biasg[4], wx[4][4];
#pragma unroll
    for (int tg = 0; tg < 4; ++tg) {
        const int n = dir * 1024 + tg * 256 + j;
        biasg[tg] = bih[n] + bhh[n];
#pragma unroll
        for (int d2 = 0; d2 < 4; ++d2) wx[tg][d2] = wih[(size_t)n * 4 + d2];
    }

    float c4[4] = {0.f, 0.f, 0.f, 0.f};
    const int arow  = bh * 64 + wave * 16 + l15;   // A-operand row (load)
    const int mrow0 = bh * 64 + wave * 16 + q * 4; // C rows base (update)
    int* fgrp = flags + (dir * 2 + bh) * 16;
    int budget = 30000000;                         // spin bail-out (no hangs)

#pragma unroll 1
    for (int s = 1; s <= T_SEQ; ++s) {
        if (s > 1) {
            if (wave == 0 && lane < 16) {
                const int need = s - 1;
                while (__hip_atomic_load(fgrp + lane, __ATOMIC_RELAXED,
                                         __HIP_MEMORY_SCOPE_AGENT) < need) {
                    if (--budget < 0) break;
                }
            }
            if (wave == 0) __threadfence();        // acquire: inv L1/L2
            __syncthreads();
        }
        const int t_in = dir ? (T_SEQ - s) : (s - 1);

        // acc init: bias + x(t) . w_ih
        f32x4 xv[4];
#pragma unroll
        for (int r = 0; r < 4; ++r)
            xv[r] = *(const f32x4*)(x + ((size_t)(mrow0 + r) * T_SEQ + t_in) * 4);
        f32x4 acc[4];
#pragma unroll
        for (int tg = 0; tg < 4; ++tg) {
#pragma unroll
            for (int r = 0; r < 4; ++r) {
                acc[tg][r] = biasg[tg] + xv[r][0] * wx[tg][0] + xv[r][1] * wx[tg][1]
                                       + xv[r][2] * wx[tg][2] + xv[r][3] * wx[tg][3];
            }
        }
        // recurrent GEMM: h_prev (slot s-1) x Whh^T
        const bf16* hsrc = h0 + ((size_t)(dir * 513 + (s - 1)) * BATCH + arow) * HID + q * 8;
#pragma unroll
        for (int kt = 0; kt < 8; ++kt) {
            const bf16x8 Af = *(const bf16x8*)(hsrc + kt * 32);
            acc[0] = __builtin_amdgcn_mfma_f32_16x16x32_bf16(Af, Bf[0][kt], acc[0], 0, 0, 0);
            acc[1] = __builtin_amdgcn_mfma_f32_16x16x32_bf16(Af, Bf[1][kt], acc[1], 0, 0, 0);
            acc[2] = __builtin_amdgcn_mfma_f32_16x16x32_bf16(Af, Bf[2][kt], acc[2], 0, 0, 0);
            acc[3] = __builtin_amdgcn_mfma_f32_16x16x32_bf16(Af, Bf[3][kt], acc[3], 0, 0, 0);
        }
        // cell update + h write (slot s)
        bf16* hdst = h0 + (size_t)(dir * 513 + s) * BATCH * HID;
#pragma unroll
        for (int r = 0; r < 4; ++r) {
            const float iv = fsig(acc[0][r]);
            const float fv = fsig(acc[1][r]);
            const float gv = ftanh(acc[2][r]);
            const float ov = fsig(acc[3][r]);
            c4[r] = fv * c4[r] + iv * gv;
            const float hv = ov * ftanh(c4[r]);
            hdst[(size_t)(mrow0 + r) * HID + j] = (bf16)hv;
        }
        __syncthreads();
        if (tid == 0) {
            __threadfence();                       // release: wb L2 before flag
            __hip_atomic_store(fgrp + g, s, __ATOMIC_RELAXED, __HIP_MEMORY_SCOPE_AGENT);
        }
    }
}

// ---------------------------------------------------------------------------
// Layer 1: grid 128 = dir(2) x batch-quarter(4) x gate-group(16).
// Block: M=32 rows, N=64 cols, K=768 ([h1_prev|h0f|h0b]). Waves split N by
// gate (wave w = gate w, 16 cols). A staged in LDS (pad 776 vs 768 -> no
// bank conflicts). Gate exchange through LDS; pooling in registers.
// ---------------------------------------------------------------------------
__global__ __launch_bounds__(256, 1) void k_l1(
    const float* __restrict__ wih1, const float* __restrict__ whh1,
    const float* __restrict__ bih1, const float* __restrict__ bhh1,
    bf16* __restrict__ h0, bf16* __restrict__ h1,
    float* __restrict__ pooled, int* __restrict__ flags)
{
    __shared__ bf16 As[32][776];
    __shared__ float Gs[4][32][16];

    const int blk = blockIdx.x;
    const int dir = blk >> 6, bq = (blk >> 4) & 3, g = blk & 15;
    const int tid = threadIdx.x, wave = tid >> 6, lane = tid & 63;
    const int l15 = lane & 15, q = lane >> 4;
    const int n = dir * 1024 + wave * 256 + g * 16 + l15;  // this wave = gate `wave`

    // B fragments: 24 x 4 VGPR = 96 VGPRs. k<256 -> Whh1, else Wih1[k-256].
    bf16x8 Bf[24];
#pragma unroll
    for (int kt = 0; kt < 24; ++kt) {
        const int k = kt * 32 + q * 8;
        const float* src = (kt < 8) ? (whh1 + (size_t)n * 256 + k)
                                    : (wih1 + (size_t)n * 512 + (k - 256));
        f32x4 aa = *(const f32x4*)src;
        f32x4 bb = *(const f32x4*)(src + 4);
        bf16x8 f;
        f[0] = (bf16)aa[0]; f[1] = (bf16)aa[1]; f[2] = (bf16)aa[2]; f[3] = (bf16)aa[3];
        f[4] = (bf16)bb[0]; f[5] = (bf16)bb[1]; f[6] = (bf16)bb[2]; f[7] = (bf16)bb[3];
        Bf[kt] = f;
    }
    const float biasw = bih1[n] + bhh1[n];
    const int r0 = tid >> 4, colu = tid & 15;     // update mapping: 2 rows/thread
    float cst[2] = {0.f, 0.f}, pool[2] = {0.f, 0.f};
    int* fgrp = flags + (dir * 4 + bq) * 16;
    int budget = 30000000;

#pragma unroll 1
    for (int s = 1; s <= T_SEQ; ++s) {
        if (s > 1) {
            if (wave == 0 && lane < 16) {
                const int need = s - 1;
                while (__hip_atomic_load(fgrp + lane, __ATOMIC_RELAXED,
                                         __HIP_MEMORY_SCOPE_AGENT) < need) {
                    if (--budget < 0) break;
                }
            }
            if (wave == 0) __threadfence();
        }
        __syncthreads();

        // stage A[32][768] into LDS: [h1_prev | h0_fwd(t) | h0_bwd(t)]
        const int slotf = dir ? (513 - s) : s;     // h0 fwd slot for time t
        const int slotb = dir ? s : (513 - s);     // h0 bwd slot for time t
        const size_t h1base = ((size_t)(dir * 2 + ((s - 1) & 1))) * BATCH * HID;
#pragma unroll
        for (int i = 0; i < 12; ++i) {
            const int cq = tid + 256 * i;          // 0..3071 chunks of 8 bf16
            const int row = cq / 96;
            const int kb = cq - row * 96;
            const int grow = bq * 32 + row;
            const bf16* src;
            if (kb < 32)
                src = h1 + h1base + (size_t)grow * HID + kb * 8;
            else if (kb < 64)
                src = h0 + ((size_t)slotf * BATCH + grow) * HID + (kb - 32) * 8;
            else
                src = h0 + ((size_t)(513 + slotb) * BATCH + grow) * HID + (kb - 64) * 8;
            *(bf16x8*)(&As[row][kb * 8]) = *(const bf16x8*)src;
        }
        __syncthreads();

        // GEMM: 2 M-tiles x 24 K-steps
        f32x4 acc0 = {biasw, biasw, biasw, biasw};
        f32x4 acc1 = acc0;
#pragma unroll
        for (int kt = 0; kt < 24; ++kt) {
            const bf16x8 a0 = *(const bf16x8*)(&As[l15][kt * 32 + q * 8]);
            const bf16x8 a1 = *(const bf16x8*)(&As[16 + l15][kt * 32 + q * 8]);
            acc0 = __builtin_amdgcn_mfma_f32_16x16x32_bf16(a0, Bf[kt], acc0, 0, 0, 0);
            acc1 = __builtin_amdgcn_mfma_f32_16x16x32_bf16(a1, Bf[kt], acc1, 0, 0, 0);
        }
        // gate exchange via LDS
#pragma unroll
        for (int r = 0; r < 4; ++r) {
            Gs[wave][q * 4 + r][l15]      = acc0[r];
            Gs[wave][16 + q * 4 + r][l15] = acc1[r];
        }
        __syncthreads();

        // cell update: thread handles rows r0, r0+16 of hidden unit colu
#pragma unroll
        for (int rr = 0; rr < 2; ++rr) {
            const int r = r0 + rr * 16;
            const float iv = fsig(Gs[0][r][colu]);
            const float fv = fsig(Gs[1][r][colu]);
            const float gv = ftanh(Gs[2][r][colu]);
            const float ov = fsig(Gs[3][r][colu]);
            cst[rr] = fv * cst[rr] + iv * gv;
            const float hv = ov * ftanh(cst[rr]);
            pool[rr] += hv;
            h1[((size_t)(dir * 2 + (s & 1)) * BATCH + bq * 32 + r) * HID + g * 16 + colu] =
                (bf16)hv;
        }
        __syncthreads();
        if (tid == 0) {
            __threadfence();
            __hip_atomic_store(fgrp + g, s, __ATOMIC_RELAXED, __HIP_MEMORY_SCOPE_AGENT);
        }
    }
    // mean pool epilogue
#pragma unroll
    for (int rr = 0; rr < 2; ++rr) {
        const int r = r0 + rr * 16;
        pooled[((size_t)dir * BATCH + bq * 32 + r) * HID + g * 16 + colu] =
            pool[rr] * (1.0f / 512.0f);
    }
}

// ---------------------------------------------------------------------------
__global__ void k_fc(const float* __restrict__ pooled, const float* __restrict__ fcw,
                     const float* __restrict__ fcb, float* __restrict__ out)
{
    const int b = blockIdx.x;            // 128 blocks, 64 threads
    const int lane = threadIdx.x;
    float s0 = 0.f, s1 = 0.f;
#pragma unroll
    for (int jj = 0; jj < 8; ++jj) {
        const int jx = lane + jj * 64;   // 0..511
        const float p = (jx < 256) ? pooled[(size_t)b * 256 + jx]
                                   : pooled[32768 + (size_t)b * 256 + (jx - 256)];
        s0 += p * fcw[jx];
        s1 += p * fcw[512 + jx];
    }
#pragma unroll
    for (int off = 32; off > 0; off >>= 1) {
        s0 += __shfl_down(s0, off);
        s1 += __shfl_down(s1, off);
    }
    if (lane == 0) {
        out[b * 2 + 0] = s0 + fcb[0];
        out[b * 2 + 1] = s1 + fcb[1];
    }
}

// ---------------------------------------------------------------------------
extern "C" void kernel_launch(void* const* d_in, const int* in_sizes, int n_in,
                              void* d_out, int out_size, void* d_ws, size_t ws_size,
                              hipStream_t stream)
{
    const float* x    = (const float*)d_in[0];
    const float* wih0 = (const float*)d_in[1];
    const float* whh0 = (const float*)d_in[2];
    const float* bih0 = (const float*)d_in[3];
    const float* bhh0 = (const float*)d_in[4];
    const float* wih1 = (const float*)d_in[5];
    const float* whh1 = (const float*)d_in[6];
    const float* bih1 = (const float*)d_in[7];
    const float* bhh1 = (const float*)d_in[8];
    const float* fcw  = (const float*)d_in[9];
    const float* fcb  = (const float*)d_in[10];
    float* out = (float*)d_out;

    char* ws = (char*)d_ws;
    bf16* h0      = (bf16*)ws;
    bf16* h1      = (bf16*)(ws + H0_BYTES);
    float* pooled = (float*)(ws + H0_BYTES + H1_BYTES);
    int* flags0   = (int*)(ws + FL0_OFF);
    int* flags1   = (int*)(ws + FL1_OFF);

    k_init<<<dim3(64), dim3(256), 0, stream>>>((unsigned int*)ws, flags0, flags1);
    k_l0<<<dim3(64), dim3(256), 0, stream>>>(x, wih0, whh0, bih0, bhh0, h0, flags0);
    k_l1<<<dim3(128), dim3(256), 0, stream>>>(wih1, whh1, bih1, bhh1, h0, h1, pooled, flags1);
    k_fc<<<dim3(128), dim3(64), 0, stream>>>(pooled, fcw, fcb, out);
}

// Round 3
// 4815.604 us; speedup vs baseline: 1.8841x; 1.8841x over previous
//
#include <hip/hip_runtime.h>
#include <hip/hip_bf16.h>

// ---------------------------------------------------------------------------
// Bidirectional 2-layer LSTM (B=128, T=512, H=256, INPUT=4) + mean-pool + FC.
//
// Round-3: fence-free exchange via AGENT-scope relaxed atomics (compiler-
// generated cache-bypass ops; no inline-asm loads, no buffer_inv/wbl2):
//  - h exchange data: atomic u64/u32 stores -> MALL; __syncthreads drains
//    vmcnt before tid0 publishes the per-block flag (relaxed atomic store).
//  - consumers poll flags (relaxed atomic) then read h via relaxed atomic
//    u64 loads; x / weights / h0-in-k_l1 stay on plain cached loads.
//  - k_l1: h0 part of the GEMM (32/48 MFMAs) runs PRE-poll; racy h1_prev
//    staged once per block into LDS (kills 4x per-wave redundancy).
// ---------------------------------------------------------------------------

typedef __bf16 bf16;
typedef __bf16 bf16x8 __attribute__((ext_vector_type(8)));
typedef float  f32x4  __attribute__((ext_vector_type(4)));
typedef unsigned int u32;
typedef unsigned long long u64;
typedef u64 u64x2 __attribute__((ext_vector_type(2)));

#define T_SEQ 512
#define BATCH 128
#define HID   256

// ws layout (bytes)
#define H0_BYTES   67239936ULL                  // bf16 [2][513][128][256]
#define H1_BYTES   262144ULL                    // bf16 [2][2][128][256] ring
#define POOL_BYTES 262144ULL                    // f32  [2][128][256]
#define FL0_OFF    (H0_BYTES + H1_BYTES + POOL_BYTES)
#define FL1_OFF    (FL0_OFF + 4096ULL)          // flags0: 4 grp x 16 x 16 ints

#define MFMA16(a, b, c) __builtin_amdgcn_mfma_f32_16x16x32_bf16((a), (b), (c), 0, 0, 0)
#define AL(p)     __hip_atomic_load((p), __ATOMIC_RELAXED, __HIP_MEMORY_SCOPE_AGENT)
#define AS(p, v)  __hip_atomic_store((p), (v), __ATOMIC_RELAXED, __HIP_MEMORY_SCOPE_AGENT)

__device__ __forceinline__ float fsig(float v) {
    return __builtin_amdgcn_rcpf(1.0f + __expf(-v));
}
__device__ __forceinline__ float ftanh(float v) {
    float a = fabsf(v);
    float e = __expf(-2.0f * a);
    float r = (1.0f - e) * __builtin_amdgcn_rcpf(1.0f + e);
    return v < 0.0f ? -r : r;
}

// ---------------------------------------------------------------------------
__global__ void k_init(unsigned int* ws_u, int* flags0, int* flags1) {
    const int t = blockIdx.x * 256 + threadIdx.x;       // 0..16383
    ws_u[t] = 0u;                                       // h0[0][slot0]
    ws_u[(size_t)513 * 16384 + t] = 0u;                 // h0[1][slot0]
    unsigned int* h1u = ws_u + (H0_BYTES / 4);
    h1u[t] = 0u;                                        // h1 dir0 parity0
    h1u[32768 + t] = 0u;                                // h1 dir1 parity0
    if (t < 1024) flags0[t] = 0;
    if (t < 2048) flags1[t] = 0;
}

// ---------------------------------------------------------------------------
// Layer 0: grid 64 = dir(2) x batch-half(2) x gate-group(16). 256 thr/block.
// M=64 rows, N=64 cols (i,f,g,o of 16 hidden units), K=256. Waves split M.
// Weights: 4x8 B-fragments = 128 VGPRs, loaded once.
// ---------------------------------------------------------------------------
__global__ __launch_bounds__(256, 1) void k_l0(
    const float* __restrict__ x, const float* __restrict__ wih,
    const float* __restrict__ whh, const float* __restrict__ bih,
    const float* __restrict__ bhh, bf16* __restrict__ h0,
    int* __restrict__ flags)
{
    __shared__ __align__(16) bf16 Hs[64][20];          // pad 20: conflict-free

    const int blk = blockIdx.x;
    const int dir = blk >> 5, bh = (blk >> 4) & 1, g = blk & 15;
    const int tid = threadIdx.x, wave = tid >> 6, lane = tid & 63;
    const int l15 = lane & 15, q = lane >> 4;
    const int j = g * 16 + l15;                 // hidden unit (column)

    // B fragments: Bf[gate][kt], n = gate*256 + j, k = kt*32 + q*8 .. +8
    bf16x8 Bf[4][8];
#pragma unroll
    for (int tg = 0; tg < 4; ++tg) {
        const float* wr = whh + ((size_t)(dir * 1024 + tg * 256 + j)) * 256 + q * 8;
#pragma unroll
        for (int kt = 0; kt < 8; ++kt) {
            f32x4 aa = *(const f32x4*)(wr + kt * 32);
            f32x4 bb = *(const f32x4*)(wr + kt * 32 + 4);
            bf16x8 f;
            f[0] = (bf16)aa[0]; f[1] = (bf16)aa[1]; f[2] = (bf16)aa[2]; f[3] = (bf16)aa[3];
            f[4] = (bf16)bb[0]; f[5] = (bf16)bb[1]; f[6] = (bf16)bb[2]; f[7] = (bf16)bb[3];
            Bf[tg][kt] = f;
        }
    }
    float biasg[4], wx[4][4];
#pragma unroll
    for (int tg = 0; tg < 4; ++tg) {
        const int n = dir * 1024 + tg * 256 + j;
        biasg[tg] = bih[n] + bhh[n];
#pragma unroll
        for (int d2 = 0; d2 < 4; ++d2) wx[tg][d2] = wih[(size_t)n * 4 + d2];
    }

    float c4[4] = {0.f, 0.f, 0.f, 0.f};
    const int arow  = bh * 64 + wave * 16 + l15;   // A-operand row (load)
    const int lrow0 = wave * 16 + q * 4;           // local C rows base
    const int mrow0 = bh * 64 + lrow0;             // global C rows base
    const int srow = tid >> 2, scg = (tid & 3) * 4; // 8B-store mapping
    int* fgrp = flags + (dir * 2 + bh) * 256;      // 16 flags, stride 16
    int budget = 30000000;

#pragma unroll 1
    for (int s = 1; s <= T_SEQ; ++s) {
        const int t_in = dir ? (T_SEQ - s) : (s - 1);

        // --- pre-poll: bias + x(t).w_ih (non-racy, cached loads) ---
        f32x4 xv[4];
#pragma unroll
        for (int r = 0; r < 4; ++r)
            xv[r] = *(const f32x4*)(x + ((size_t)(mrow0 + r) * T_SEQ + t_in) * 4);
        f32x4 acc[4];
#pragma unroll
        for (int tg = 0; tg < 4; ++tg) {
#pragma unroll
            for (int r = 0; r < 4; ++r) {
                acc[tg][r] = biasg[tg] + xv[r][0] * wx[tg][0] + xv[r][1] * wx[tg][1]
                                       + xv[r][2] * wx[tg][2] + xv[r][3] * wx[tg][3];
            }
        }

        // --- poll producers (per-wave; relaxed agent loads -> MALL) ---
        if (lane < 16) {
            const int need = s - 1;
            while (AL(fgrp + lane * 16) < need) {
                if (--budget < 0) break;
            }
        }
        asm volatile("" ::: "memory");

        // --- racy A loads: relaxed agent atomic u64 (bypass, from MALL) ---
        const u64* hsrc = (const u64*)(h0 + ((size_t)(dir * 513 + (s - 1)) * BATCH + arow) * HID)
                          + q * 2;
        u64 av[16];
#pragma unroll
        for (int kt = 0; kt < 8; ++kt) {
            av[2 * kt]     = AL(hsrc + kt * 8);
            av[2 * kt + 1] = AL(hsrc + kt * 8 + 1);
        }
#pragma unroll
        for (int kt = 0; kt < 8; ++kt) {
            u64x2 t2; t2[0] = av[2 * kt]; t2[1] = av[2 * kt + 1];
            const bf16x8 A = __builtin_bit_cast(bf16x8, t2);
            acc[0] = MFMA16(A, Bf[0][kt], acc[0]);
            acc[1] = MFMA16(A, Bf[1][kt], acc[1]);
            acc[2] = MFMA16(A, Bf[2][kt], acc[2]);
            acc[3] = MFMA16(A, Bf[3][kt], acc[3]);
        }

        // --- cell update -> LDS repack ---
#pragma unroll
        for (int r = 0; r < 4; ++r) {
            const float iv = fsig(acc[0][r]);
            const float fv = fsig(acc[1][r]);
            const float gv = ftanh(acc[2][r]);
            const float ov = fsig(acc[3][r]);
            c4[r] = fv * c4[r] + iv * gv;
            const float hv = ov * ftanh(c4[r]);
            Hs[lrow0 + r][l15] = (bf16)hv;
        }
        __syncthreads();
        // 8B agent-atomic store per thread -> MALL
        {
            const u64 hv8 = *(const u64*)&Hs[srow][scg];
            u64* dst = (u64*)(h0 + ((size_t)(dir * 513 + s) * BATCH + bh * 64 + srow) * HID
                              + g * 16 + scg);
            AS(dst, hv8);
        }
        __syncthreads();                       // drains vmcnt before flag
        if (tid == 0) AS(fgrp + g * 16, s);
    }
}

// ---------------------------------------------------------------------------
// Layer 1: grid 128 = dir(2) x batch-quarter(4) x gate-group(16).
// M=32 rows, N=64 cols, K=768 ([h1_prev|h0f|h0b]). Waves split N by gate.
// h0 part of GEMM pre-poll on cached loads; racy h1_prev staged into LDS
// once per block (atomic u64 loads), fragments via ds_read_b128.
// ---------------------------------------------------------------------------
__global__ __launch_bounds__(256, 1) void k_l1(
    const float* __restrict__ wih1, const float* __restrict__ whh1,
    const float* __restrict__ bih1, const float* __restrict__ bhh1,
    bf16* __restrict__ h0, bf16* __restrict__ h1,
    float* __restrict__ pooled, int* __restrict__ flags)
{
    __shared__ float Gs[4][32][17];                    // gate exchange (pad 17)
    __shared__ __align__(16) bf16 Hs[32][20];          // h repack (pad 20)
    __shared__ __align__(16) bf16 As1[32][264];        // h1_prev stage (pad 264)

    const int blk = blockIdx.x;
    const int dir = blk >> 6, bq = (blk >> 4) & 3, g = blk & 15;
    const int tid = threadIdx.x, wave = tid >> 6, lane = tid & 63;
    const int l15 = lane & 15, q = lane >> 4;
    const int n = dir * 1024 + wave * 256 + g * 16 + l15;  // wave = gate

    // B fragments: 24 x 4 VGPR = 96 VGPRs. kt<8 -> Whh1; 8..15 -> h0f part
    // of Wih1; 16..23 -> h0b part.
    bf16x8 Bf[24];
#pragma unroll
    for (int kt = 0; kt < 24; ++kt) {
        const int k = kt * 32 + q * 8;
        const float* src = (kt < 8) ? (whh1 + (size_t)n * 256 + k)
                                    : (wih1 + (size_t)n * 512 + (k - 256));
        f32x4 aa = *(const f32x4*)src;
        f32x4 bb = *(const f32x4*)(src + 4);
        bf16x8 f;
        f[0] = (bf16)aa[0]; f[1] = (bf16)aa[1]; f[2] = (bf16)aa[2]; f[3] = (bf16)aa[3];
        f[4] = (bf16)bb[0]; f[5] = (bf16)bb[1]; f[6] = (bf16)bb[2]; f[7] = (bf16)bb[3];
        Bf[kt] = f;
    }
    const float biasw = bih1[n] + bhh1[n];
    const int r0 = tid >> 4, colu = tid & 15;     // update: rows r0, r0+16
    float cst[2] = {0.f, 0.f}, pool[2] = {0.f, 0.f};
    int* fgrp = flags + (dir * 4 + bq) * 256;
    int budget = 30000000;

#pragma unroll 1
    for (int s = 1; s <= T_SEQ; ++s) {
        const int slotf = dir ? (513 - s) : s;     // h0 fwd slot for time t
        const int slotb = dir ? s : (513 - s);     // h0 bwd slot for time t

        // --- pre-poll: h0 contribution (non-racy, cached) ---
        f32x4 acc0 = {biasw, biasw, biasw, biasw};
        f32x4 acc1 = acc0;
        const bf16* f0 = h0 + ((size_t)slotf * BATCH + bq * 32 + l15) * HID + q * 8;
        const bf16* b0 = h0 + ((size_t)(513 + slotb) * BATCH + bq * 32 + l15) * HID + q * 8;
#pragma unroll
        for (int kt = 0; kt < 8; ++kt) {
            const bf16x8 af0 = *(const bf16x8*)(f0 + kt * 32);
            const bf16x8 af1 = *(const bf16x8*)(f0 + 16 * HID + kt * 32);
            acc0 = MFMA16(af0, Bf[8 + kt], acc0);
            acc1 = MFMA16(af1, Bf[8 + kt], acc1);
        }
#pragma unroll
        for (int kt = 0; kt < 8; ++kt) {
            const bf16x8 ab0 = *(const bf16x8*)(b0 + kt * 32);
            const bf16x8 ab1 = *(const bf16x8*)(b0 + 16 * HID + kt * 32);
            acc0 = MFMA16(ab0, Bf[16 + kt], acc0);
            acc1 = MFMA16(ab1, Bf[16 + kt], acc1);
        }

        // --- poll producers ---
        if (lane < 16) {
            const int need = s - 1;
            while (AL(fgrp + lane * 16) < need) {
                if (--budget < 0) break;
            }
        }
        asm volatile("" ::: "memory");

        // --- stage racy h1_prev [32][256] into LDS (atomic u64 loads) ---
        {
            const u64* hb = (const u64*)(h1 + ((size_t)(dir * 2 + ((s - 1) & 1)) * BATCH
                                               + bq * 32) * HID);
#pragma unroll
            for (int i = 0; i < 4; ++i) {
                const int chunk = tid + 256 * i;         // 0..1023 (16B chunks)
                const int row = chunk >> 5, cc = chunk & 31;
                const u64* src = hb + (size_t)row * 32 + cc;   // row*256 elems /8... (32 u64/row... see note)
                // NOTE: row stride in u64 = HID/4 = 64. chunk cc indexes 8-elem
                // groups -> u64 offset cc*2.
                const u64 lo = AL(hb + (size_t)row * 64 + cc * 2);
                const u64 hi = AL(hb + (size_t)row * 64 + cc * 2 + 1);
                (void)src;
                u64x2 t2; t2[0] = lo; t2[1] = hi;
                *(bf16x8*)(&As1[row][cc * 8]) = __builtin_bit_cast(bf16x8, t2);
            }
        }
        __syncthreads();

        // --- h1_prev GEMM from LDS: 2 M-tiles x 8 K-steps ---
#pragma unroll
        for (int kt = 0; kt < 8; ++kt) {
            const bf16x8 a0 = *(const bf16x8*)(&As1[l15][kt * 32 + q * 8]);
            const bf16x8 a1 = *(const bf16x8*)(&As1[16 + l15][kt * 32 + q * 8]);
            acc0 = MFMA16(a0, Bf[kt], acc0);
            acc1 = MFMA16(a1, Bf[kt], acc1);
        }

        // --- gate exchange via LDS ---
#pragma unroll
        for (int r = 0; r < 4; ++r) {
            Gs[wave][q * 4 + r][l15]      = acc0[r];
            Gs[wave][16 + q * 4 + r][l15] = acc1[r];
        }
        __syncthreads();

        // --- cell update: rows r0, r0+16 of hidden unit colu ---
#pragma unroll
        for (int rr = 0; rr < 2; ++rr) {
            const int r = r0 + rr * 16;
            const float iv = fsig(Gs[0][r][colu]);
            const float fv = fsig(Gs[1][r][colu]);
            const float gv = ftanh(Gs[2][r][colu]);
            const float ov = fsig(Gs[3][r][colu]);
            cst[rr] = fv * cst[rr] + iv * gv;
            const float hv = ov * ftanh(cst[rr]);
            pool[rr] += hv;
            Hs[r][colu] = (bf16)hv;
        }
        __syncthreads();
        // 4B agent-atomic store per thread
        {
            const int lrow = tid >> 3, c2 = (tid & 7) * 2;
            const u32 hv4 = *(const u32*)&Hs[lrow][c2];
            u32* dst = (u32*)(h1 + ((size_t)(dir * 2 + (s & 1)) * BATCH + bq * 32 + lrow) * HID
                              + g * 16 + c2);
            AS(dst, hv4);
        }
        __syncthreads();                       // drains vmcnt before flag
        if (tid == 0) AS(fgrp + g * 16, s);
    }
    // mean pool epilogue
#pragma unroll
    for (int rr = 0; rr < 2; ++rr) {
        const int r = r0 + rr * 16;
        pooled[((size_t)dir * BATCH + bq * 32 + r) * HID + g * 16 + colu] =
            pool[rr] * (1.0f / 512.0f);
    }
}

// ---------------------------------------------------------------------------
__global__ void k_fc(const float* __restrict__ pooled, const float* __restrict__ fcw,
                     const float* __restrict__ fcb, float* __restrict__ out)
{
    const int b = blockIdx.x;            // 128 blocks, 64 threads
    const int lane = threadIdx.x;
    float s0 = 0.f, s1 = 0.f;
#pragma unroll
    for (int jj = 0; jj < 8; ++jj) {
        const int jx = lane + jj * 64;   // 0..511
        const float p = (jx < 256) ? pooled[(size_t)b * 256 + jx]
                                   : pooled[32768 + (size_t)b * 256 + (jx - 256)];
        s0 += p * fcw[jx];
        s1 += p * fcw[512 + jx];
    }
#pragma unroll
    for (int off = 32; off > 0; off >>= 1) {
        s0 += __shfl_down(s0, off);
        s1 += __shfl_down(s1, off);
    }
    if (lane == 0) {
        out[b * 2 + 0] = s0 + fcb[0];
        out[b * 2 + 1] = s1 + fcb[1];
    }
}

// ---------------------------------------------------------------------------
extern "C" void kernel_launch(void* const* d_in, const int* in_sizes, int n_in,
                              void* d_out, int out_size, void* d_ws, size_t ws_size,
                              hipStream_t stream)
{
    const float* x    = (const float*)d_in[0];
    const float* wih0 = (const float*)d_in[1];
    const float* whh0 = (const float*)d_in[2];
    const float* bih0 = (const float*)d_in[3];
    const float* bhh0 = (const float*)d_in[4];
    const float* wih1 = (const float*)d_in[5];
    const float* whh1 = (const float*)d_in[6];
    const float* bih1 = (const float*)d_in[7];
    const float* bhh1 = (const float*)d_in[8];
    const float* fcw  = (const float*)d_in[9];
    const float* fcb  = (const float*)d_in[10];
    float* out = (float*)d_out;

    char* ws = (char*)d_ws;
    bf16* h0      = (bf16*)ws;
    bf16* h1      = (bf16*)(ws + H0_BYTES);
    float* pooled = (float*)(ws + H0_BYTES + H1_BYTES);
    int* flags0   = (int*)(ws + FL0_OFF);
    int* flags1   = (int*)(ws + FL1_OFF);

    k_init<<<dim3(64), dim3(256), 0, stream>>>((unsigned int*)ws, flags0, flags1);
    k_l0<<<dim3(64), dim3(256), 0, stream>>>(x, wih0, whh0, bih0, bhh0, h0, flags0);
    k_l1<<<dim3(128), dim3(256), 0, stream>>>(wih1, whh1, bih1, bhh1, h0, h1, pooled, flags1);
    k_fc<<<dim3(128), dim3(64), 0, stream>>>(pooled, fcw, fcb, out);
}